// Round 1
// baseline (3938.413 us; speedup 1.0000x reference)
//
#include <hip/hip_runtime.h>
#include <math.h>

// ---- problem constants ----
constexpr int Bc   = 32;
constexpr int Nc   = 196;
constexpr int Cc   = 768;
constexpr int Hc   = 12;
constexpr int HDc  = 64;
constexpr int Lc   = 4;
constexpr int DFFc = 3072;
constexpr int NCAT = 2 * Nc;          // 392
constexpr int Mrows = Bc * Nc;        // 6272
constexpr float SCALE_C = 0.03608439182435161f;  // 768^-0.5
constexpr float SCALE_H = 0.125f;                // 64^-0.5

__device__ inline float gelu_exact(float v) {
    return 0.5f * v * (1.0f + erff(v * 0.7071067811865476f));
}

// =====================================================================
// Latent scores: probs[b][l][j] = softmax_j( lat[l] . concat[b][j] * C^-0.5 )
// grid (B, L), block 256
// =====================================================================
__global__ __launch_bounds__(256) void lat_scores_ker(
    const float* __restrict__ x, const float* __restrict__ y,
    const float* __restrict__ lat, float* __restrict__ probs)
{
    int b = blockIdx.x, l = blockIdx.y;
    __shared__ float s[NCAT];
    __shared__ float redm[4];
    __shared__ float reds[4];
    const float* lrow = lat + (size_t)l * Cc;
    int w = threadIdx.x >> 6, lane = threadIdx.x & 63;

    for (int j = w; j < NCAT; j += 4) {
        const float* row = (j < Nc) ? x + ((size_t)b * Nc + j) * Cc
                                    : y + ((size_t)b * Nc + (j - Nc)) * Cc;
        float p = 0.f;
        for (int c = lane; c < Cc; c += 64) p += lrow[c] * row[c];
        #pragma unroll
        for (int o = 32; o; o >>= 1) p += __shfl_xor(p, o);
        if (lane == 0) s[j] = p * SCALE_C;
    }
    __syncthreads();

    float m = -INFINITY;
    for (int j = threadIdx.x; j < NCAT; j += 256) m = fmaxf(m, s[j]);
    #pragma unroll
    for (int o = 32; o; o >>= 1) m = fmaxf(m, __shfl_xor(m, o));
    if (lane == 0) redm[w] = m;
    __syncthreads();
    m = fmaxf(fmaxf(redm[0], redm[1]), fmaxf(redm[2], redm[3]));

    float sum = 0.f;
    for (int j = threadIdx.x; j < NCAT; j += 256) {
        float e = expf(s[j] - m);
        s[j] = e;
        sum += e;
    }
    #pragma unroll
    for (int o = 32; o; o >>= 1) sum += __shfl_xor(sum, o);
    if (lane == 0) reds[w] = sum;
    __syncthreads();
    sum = reds[0] + reds[1] + reds[2] + reds[3];
    float inv = 1.f / sum;
    for (int j = threadIdx.x; j < NCAT; j += 256)
        probs[((size_t)b * Lc + l) * NCAT + j] = s[j] * inv;
}

// =====================================================================
// fused[b][l][c] = sum_j probs[b][l][j] * concat[b][j][c]
// grid B, block 256; each thread owns 12 outputs: o = t + 256*k
// For t<256: l = k/3, c = t + 256*(k%3)  (since o = t + 256k, L*C = 3072)
// =====================================================================
__global__ __launch_bounds__(256) void lat_fused_ker(
    const float* __restrict__ x, const float* __restrict__ y,
    const float* __restrict__ probs, float* __restrict__ fused)
{
    int b = blockIdx.x;
    int t = threadIdx.x;
    __shared__ float p[Lc * NCAT];
    for (int idx = t; idx < Lc * NCAT; idx += 256)
        p[idx] = probs[(size_t)b * Lc * NCAT + idx];
    __syncthreads();

    float acc[12];
    #pragma unroll
    for (int k = 0; k < 12; ++k) acc[k] = 0.f;

    for (int j = 0; j < NCAT; ++j) {
        const float* row = (j < Nc) ? x + ((size_t)b * Nc + j) * Cc
                                    : y + ((size_t)b * Nc + (j - Nc)) * Cc;
        float r0 = row[t];
        float r1 = row[t + 256];
        float r2 = row[t + 512];
        float pl0 = p[0 * NCAT + j], pl1 = p[1 * NCAT + j];
        float pl2 = p[2 * NCAT + j], pl3 = p[3 * NCAT + j];
        acc[0] += pl0 * r0;  acc[1] += pl0 * r1;  acc[2]  += pl0 * r2;
        acc[3] += pl1 * r0;  acc[4] += pl1 * r1;  acc[5]  += pl1 * r2;
        acc[6] += pl2 * r0;  acc[7] += pl2 * r1;  acc[8]  += pl2 * r2;
        acc[9] += pl3 * r0;  acc[10]+= pl3 * r1;  acc[11] += pl3 * r2;
    }
    #pragma unroll
    for (int k = 0; k < 12; ++k) {
        int l = k / 3, c = t + 256 * (k % 3);
        fused[(size_t)b * Lc * Cc + l * Cc + c] = acc[k];
    }
}

// =====================================================================
// inject: out = src + scale * sdpa(src, fused, fused, C^-0.5)
// grid 2*B*N blocks (stream major), block 256
// =====================================================================
__global__ __launch_bounds__(256) void inject_ker(
    const float* __restrict__ x, const float* __restrict__ y,
    const float* __restrict__ fused,
    const float* __restrict__ scale_a, const float* __restrict__ scale_v,
    float* __restrict__ out)
{
    int gid = blockIdx.x;
    int st = gid / Mrows;
    int bn = gid % Mrows;
    int b = bn / Nc;
    const float* src = st ? y : x;
    float scale = st ? scale_v[0] : scale_a[0];
    float* dst = out + (size_t)st * Mrows * Cc;
    const float* f = fused + (size_t)b * Lc * Cc;
    const float* row = src + (size_t)bn * Cc;

    __shared__ float sc[4];
    int w = threadIdx.x >> 6, lane = threadIdx.x & 63;
    float partial = 0.f;
    for (int c = lane; c < Cc; c += 64) partial += row[c] * f[w * Cc + c];
    #pragma unroll
    for (int o = 32; o; o >>= 1) partial += __shfl_xor(partial, o);
    if (lane == 0) sc[w] = partial * SCALE_C;
    __syncthreads();

    float s0 = sc[0], s1 = sc[1], s2 = sc[2], s3 = sc[3];
    float m = fmaxf(fmaxf(s0, s1), fmaxf(s2, s3));
    float e0 = expf(s0 - m), e1 = expf(s1 - m), e2 = expf(s2 - m), e3 = expf(s3 - m);
    float inv = 1.f / (e0 + e1 + e2 + e3);
    e0 *= inv; e1 *= inv; e2 *= inv; e3 *= inv;

    for (int c = threadIdx.x; c < Cc; c += 256) {
        float v = e0 * f[c] + e1 * f[Cc + c] + e2 * f[2 * Cc + c] + e3 * f[3 * Cc + c];
        dst[(size_t)bn * Cc + c] = row[c] + scale * v;
    }
}

// =====================================================================
// LayerNorm: one block per row
// =====================================================================
__global__ __launch_bounds__(256) void ln_ker(
    const float* __restrict__ in, const float* __restrict__ g,
    const float* __restrict__ bb, float* __restrict__ out)
{
    int row = blockIdx.x;
    __shared__ float buf[Cc];
    __shared__ float red[4];
    __shared__ float red2[4];
    const float* r = in + (size_t)row * Cc;
    int w = threadIdx.x >> 6, lane = threadIdx.x & 63;

    float s = 0.f;
    for (int c = threadIdx.x; c < Cc; c += 256) {
        float v = r[c];
        buf[c] = v;
        s += v;
    }
    #pragma unroll
    for (int o = 32; o; o >>= 1) s += __shfl_xor(s, o);
    if (lane == 0) red[w] = s;
    __syncthreads();
    float mean = (red[0] + red[1] + red[2] + red[3]) * (1.f / Cc);

    float vs = 0.f;
    for (int c = threadIdx.x; c < Cc; c += 256) {
        float d = buf[c] - mean;
        vs += d * d;
    }
    #pragma unroll
    for (int o = 32; o; o >>= 1) vs += __shfl_xor(vs, o);
    if (lane == 0) red2[w] = vs;
    __syncthreads();
    float var = (red2[0] + red2[1] + red2[2] + red2[3]) * (1.f / Cc);
    float inv = 1.f / sqrtf(var + 1e-6f);

    for (int c = threadIdx.x; c < Cc; c += 256)
        out[(size_t)row * Cc + c] = (buf[c] - mean) * inv * g[c] + bb[c];
}

// =====================================================================
// Tiled fp32 GEMM: out[M,N] = A[M,K] @ W[K,N] + bias  (+epilogue)
// EPI 0: +bias   EPI 1: gelu(+bias)   EPI 2: res + (+bias)
// BM=BN=64, BK=16, 256 threads, 4x4 per thread
// =====================================================================
template <int EPI>
__global__ __launch_bounds__(256) void gemm_ker(
    const float* __restrict__ A, const float* __restrict__ W,
    const float* __restrict__ bias, const float* __restrict__ res,
    float* __restrict__ out, int M_, int N_, int K_)
{
    __shared__ float As[16][64];   // [k][m] transposed
    __shared__ float Ws[16][64];   // [k][n]
    int t = threadIdx.x;
    int tx = t & 15, ty = t >> 4;
    int row0 = blockIdx.y * 64, col0 = blockIdx.x * 64;

    float acc[4][4] = {};

    int ar = t >> 2;                // 0..63
    int ac = (t & 3) * 4;           // 0,4,8,12
    int wr = t >> 4;                // 0..15
    int wc = (t & 15) * 4;          // 0..60

    for (int kt = 0; kt < K_; kt += 16) {
        float4 av = *reinterpret_cast<const float4*>(&A[(size_t)(row0 + ar) * K_ + kt + ac]);
        As[ac + 0][ar] = av.x;
        As[ac + 1][ar] = av.y;
        As[ac + 2][ar] = av.z;
        As[ac + 3][ar] = av.w;
        float4 wv = *reinterpret_cast<const float4*>(&W[(size_t)(kt + wr) * N_ + col0 + wc]);
        *reinterpret_cast<float4*>(&Ws[wr][wc]) = wv;
        __syncthreads();

        #pragma unroll
        for (int kk = 0; kk < 16; ++kk) {
            float4 a4 = *reinterpret_cast<const float4*>(&As[kk][ty * 4]);
            float4 w4 = *reinterpret_cast<const float4*>(&Ws[kk][tx * 4]);
            float a[4] = {a4.x, a4.y, a4.z, a4.w};
            float w[4] = {w4.x, w4.y, w4.z, w4.w};
            #pragma unroll
            for (int i = 0; i < 4; ++i)
                #pragma unroll
                for (int j = 0; j < 4; ++j)
                    acc[i][j] += a[i] * w[j];
        }
        __syncthreads();
    }

    #pragma unroll
    for (int i = 0; i < 4; ++i) {
        int rr = row0 + ty * 4 + i;
        #pragma unroll
        for (int j = 0; j < 4; ++j) {
            int cc = col0 + tx * 4 + j;
            float v = acc[i][j] + bias[cc];
            if (EPI == 1) v = gelu_exact(v);
            if (EPI == 2) v += res[(size_t)rr * N_ + cc];
            out[(size_t)rr * N_ + cc] = v;
        }
    }
}

// =====================================================================
// Multi-head attention.  qkv: [B,N,2304] rows; block per (h, b).
// K staged in LDS (padded), V read from global (L2). 4 waves, rows
// round-robin per wave; scores & probs live in registers (lane = key idx).
// =====================================================================
__global__ __launch_bounds__(256) void attn_ker(
    const float* __restrict__ qkv, float* __restrict__ o)
{
    int h = blockIdx.x, b = blockIdx.y;
    __shared__ float Ks[Nc][65];
    const size_t rs = 3 * Cc;  // 2304
    const float* base = qkv + ((size_t)b * Nc) * rs + h * HDc;

    for (int idx = threadIdx.x; idx < Nc * HDc; idx += 256) {
        int j = idx >> 6, d = idx & 63;
        Ks[j][d] = base[(size_t)j * rs + Cc + d];
    }
    __syncthreads();

    int w = threadIdx.x >> 6, lane = threadIdx.x & 63;
    int j3 = 192 + (lane & 3);

    for (int i = w; i < Nc; i += 4) {
        float qreg = base[(size_t)i * rs + lane];
        float s0 = 0.f, s1 = 0.f, s2 = 0.f, s3 = 0.f;
        #pragma unroll 8
        for (int d = 0; d < 64; ++d) {
            float qd = __shfl(qreg, d);
            s0 += qd * Ks[lane][d];
            s1 += qd * Ks[64 + lane][d];
            s2 += qd * Ks[128 + lane][d];
            s3 += qd * Ks[j3][d];
        }
        s0 *= SCALE_H; s1 *= SCALE_H; s2 *= SCALE_H;
        s3 = (lane < 4) ? s3 * SCALE_H : -INFINITY;

        float m = fmaxf(fmaxf(s0, s1), fmaxf(s2, s3));
        #pragma unroll
        for (int off = 32; off; off >>= 1) m = fmaxf(m, __shfl_xor(m, off));
        float e0 = expf(s0 - m), e1 = expf(s1 - m), e2 = expf(s2 - m);
        float e3 = (lane < 4) ? expf(s3 - m) : 0.f;
        float sum = e0 + e1 + e2 + e3;
        #pragma unroll
        for (int off = 32; off; off >>= 1) sum += __shfl_xor(sum, off);
        float inv = 1.f / sum;
        e0 *= inv; e1 *= inv; e2 *= inv; e3 *= inv;

        // out[lane] = sum_j p[j] * V[j][lane]
        const float* vbase = base + 2 * Cc + lane;
        float outv = 0.f;
        #pragma unroll 4
        for (int jj = 0; jj < 64; ++jj) {
            outv += __shfl(e0, jj) * vbase[(size_t)jj * rs];
            outv += __shfl(e1, jj) * vbase[(size_t)(64 + jj) * rs];
            outv += __shfl(e2, jj) * vbase[(size_t)(128 + jj) * rs];
        }
        #pragma unroll
        for (int jj = 0; jj < 4; ++jj)
            outv += __shfl(e3, jj) * vbase[(size_t)(192 + jj) * rs];

        o[((size_t)b * Nc + i) * Cc + h * HDc + lane] = outv;
    }
}

// =====================================================================
extern "C" void kernel_launch(void* const* d_in, const int* in_sizes, int n_in,
                              void* d_out, int out_size, void* d_ws, size_t ws_size,
                              hipStream_t stream)
{
    const float* x       = (const float*)d_in[0];
    const float* y       = (const float*)d_in[1];
    const float* latents = (const float*)d_in[2];
    const float* scale_a = (const float*)d_in[3];
    const float* scale_v = (const float*)d_in[4];

    float* out = (float*)d_out;

    float* ws = (float*)d_ws;
    float* probs  = ws;                               // B*L*NCAT   = 50176
    float* fusedb = probs  + (size_t)Bc * Lc * NCAT;  // B*L*C      = 98304
    float* tbuf   = fusedb + (size_t)Bc * Lc * Cc;    // M*C        = 4816896
    float* abuf   = tbuf   + (size_t)Mrows * Cc;      // M*C        = 4816896
    float* big    = abuf   + (size_t)Mrows * Cc;      // M*DFF      = 19267584

    // ---- latent bottleneck fusion ----
    lat_scores_ker<<<dim3(Bc, Lc), 256, 0, stream>>>(x, y, latents, probs);
    lat_fused_ker<<<Bc, 256, 0, stream>>>(x, y, probs, fusedb);
    inject_ker<<<2 * Mrows, 256, 0, stream>>>(x, y, fusedb, scale_a, scale_v, out);

    // ---- per-stream ViT block ----
    for (int p = 0; p < 2; ++p) {
        int base = 5 + 12 * p;
        const float* g1    = (const float*)d_in[base + 0];
        const float* b1    = (const float*)d_in[base + 1];
        const float* qkvw  = (const float*)d_in[base + 2];
        const float* qkvb  = (const float*)d_in[base + 3];
        const float* projw = (const float*)d_in[base + 4];
        const float* projb = (const float*)d_in[base + 5];
        const float* g2    = (const float*)d_in[base + 6];
        const float* b2    = (const float*)d_in[base + 7];
        const float* fc1w  = (const float*)d_in[base + 8];
        const float* fc1b  = (const float*)d_in[base + 9];
        const float* fc2w  = (const float*)d_in[base + 10];
        const float* fc2b  = (const float*)d_in[base + 11];

        float* X = out + (size_t)p * Mrows * Cc;

        ln_ker<<<Mrows, 256, 0, stream>>>(X, g1, b1, tbuf);
        gemm_ker<0><<<dim3(3 * Cc / 64, Mrows / 64), 256, 0, stream>>>(
            tbuf, qkvw, qkvb, nullptr, big, Mrows, 3 * Cc, Cc);
        attn_ker<<<dim3(Hc, Bc), 256, 0, stream>>>(big, abuf);
        gemm_ker<2><<<dim3(Cc / 64, Mrows / 64), 256, 0, stream>>>(
            abuf, projw, projb, X, X, Mrows, Cc, Cc);
        ln_ker<<<Mrows, 256, 0, stream>>>(X, g2, b2, tbuf);
        gemm_ker<1><<<dim3(DFFc / 64, Mrows / 64), 256, 0, stream>>>(
            tbuf, fc1w, fc1b, nullptr, big, Mrows, DFFc, Cc);
        gemm_ker<2><<<dim3(Cc / 64, Mrows / 64), 256, 0, stream>>>(
            big, fc2w, fc2b, X, X, Mrows, Cc, DFFc);
    }
}

// Round 2
// 1431.363 us; speedup vs baseline: 2.7515x; 2.7515x over previous
//
#include <hip/hip_runtime.h>
#include <hip/hip_bf16.h>
#include <math.h>

// ---- problem constants ----
constexpr int Bc   = 32;
constexpr int Nc   = 196;
constexpr int Cc   = 768;
constexpr int Hc   = 12;
constexpr int HDc  = 64;
constexpr int Lc   = 4;
constexpr int DFFc = 3072;
constexpr int NCAT = 2 * Nc;          // 392
constexpr int Mrows = Bc * Nc;        // 6272
constexpr float SCALE_C = 0.03608439182435161f;  // 768^-0.5
constexpr float SCALE_H = 0.125f;                // 64^-0.5

typedef __attribute__((ext_vector_type(8))) short short8;
typedef __attribute__((ext_vector_type(4))) float float4a;

__device__ inline float gelu_exact(float v) {
    return 0.5f * v * (1.0f + erff(v * 0.7071067811865476f));
}

__device__ inline void store_val(float* p, float v) { *p = v; }
__device__ inline void store_val(__hip_bfloat16* p, float v) { *p = __float2bfloat16(v); }

__device__ inline void gload16(const void* g, void* l) {
    __builtin_amdgcn_global_load_lds(
        (const __attribute__((address_space(1))) void*)g,
        (__attribute__((address_space(3))) void*)l, 16, 0, 0);
}

// =====================================================================
// Latent scores: one WAVE per (b,j), all 4 latents at once.
// grid = B*NCAT/4 blocks of 256.
// =====================================================================
__global__ __launch_bounds__(256) void lat_scores_ker(
    const float* __restrict__ x, const float* __restrict__ y,
    const float* __restrict__ lat, float* __restrict__ scores)
{
    int wglobal = blockIdx.x * 4 + (threadIdx.x >> 6);
    int lane = threadIdx.x & 63;
    int b = wglobal / NCAT, j = wglobal % NCAT;
    const float* row = (j < Nc) ? x + ((size_t)b * Nc + j) * Cc
                                : y + ((size_t)b * Nc + (j - Nc)) * Cc;
    float a0 = 0.f, a1 = 0.f, a2 = 0.f, a3 = 0.f;
    for (int c = lane; c < Cc; c += 64) {
        float rv = row[c];
        a0 += rv * lat[c];
        a1 += rv * lat[Cc + c];
        a2 += rv * lat[2 * Cc + c];
        a3 += rv * lat[3 * Cc + c];
    }
    #pragma unroll
    for (int o = 32; o; o >>= 1) {
        a0 += __shfl_xor(a0, o);
        a1 += __shfl_xor(a1, o);
        a2 += __shfl_xor(a2, o);
        a3 += __shfl_xor(a3, o);
    }
    if (lane == 0) {
        float* sb = scores + (size_t)b * Lc * NCAT + j;
        sb[0 * NCAT] = a0 * SCALE_C;
        sb[1 * NCAT] = a1 * SCALE_C;
        sb[2 * NCAT] = a2 * SCALE_C;
        sb[3 * NCAT] = a3 * SCALE_C;
    }
}

// =====================================================================
// softmax(scores) + fused = probs @ concat.  grid (B, 3): c-chunk of 256.
// =====================================================================
__global__ __launch_bounds__(256) void lat_fused_ker(
    const float* __restrict__ x, const float* __restrict__ y,
    const float* __restrict__ scores, float* __restrict__ fused)
{
    int b = blockIdx.x, chunk = blockIdx.y;
    int t = threadIdx.x;
    __shared__ float p[Lc][NCAT];
    for (int idx = t; idx < Lc * NCAT; idx += 256)
        (&p[0][0])[idx] = scores[(size_t)b * Lc * NCAT + idx];
    __syncthreads();
    int w = t >> 6, lane = t & 63;
    // wave w does softmax of row w
    {
        float m = -INFINITY;
        for (int j = lane; j < NCAT; j += 64) m = fmaxf(m, p[w][j]);
        #pragma unroll
        for (int o = 32; o; o >>= 1) m = fmaxf(m, __shfl_xor(m, o));
        float sum = 0.f;
        for (int j = lane; j < NCAT; j += 64) {
            float e = expf(p[w][j] - m);
            p[w][j] = e;
            sum += e;
        }
        #pragma unroll
        for (int o = 32; o; o >>= 1) sum += __shfl_xor(sum, o);
        float inv = 1.f / sum;
        for (int j = lane; j < NCAT; j += 64) p[w][j] *= inv;
    }
    __syncthreads();

    int c = chunk * 256 + t;
    float a0 = 0.f, a1 = 0.f, a2 = 0.f, a3 = 0.f;
    for (int j = 0; j < NCAT; ++j) {
        const float* row = (j < Nc) ? x + ((size_t)b * Nc + j) * Cc
                                    : y + ((size_t)b * Nc + (j - Nc)) * Cc;
        float rv = row[c];
        a0 += p[0][j] * rv;
        a1 += p[1][j] * rv;
        a2 += p[2][j] * rv;
        a3 += p[3][j] * rv;
    }
    float* fb = fused + (size_t)b * Lc * Cc + c;
    fb[0 * Cc] = a0; fb[1 * Cc] = a1; fb[2 * Cc] = a2; fb[3 * Cc] = a3;
}

// =====================================================================
// inject: out = src + scale * sdpa(src, fused, fused, C^-0.5)
// =====================================================================
__global__ __launch_bounds__(256) void inject_ker(
    const float* __restrict__ x, const float* __restrict__ y,
    const float* __restrict__ fused,
    const float* __restrict__ scale_a, const float* __restrict__ scale_v,
    float* __restrict__ out)
{
    int gid = blockIdx.x;
    int st = gid / Mrows;
    int bn = gid % Mrows;
    int b = bn / Nc;
    const float* src = st ? y : x;
    float scale = st ? scale_v[0] : scale_a[0];
    float* dst = out + (size_t)st * Mrows * Cc;
    const float* f = fused + (size_t)b * Lc * Cc;
    const float* row = src + (size_t)bn * Cc;

    __shared__ float sc[4];
    int w = threadIdx.x >> 6, lane = threadIdx.x & 63;
    float partial = 0.f;
    for (int c = lane; c < Cc; c += 64) partial += row[c] * f[w * Cc + c];
    #pragma unroll
    for (int o = 32; o; o >>= 1) partial += __shfl_xor(partial, o);
    if (lane == 0) sc[w] = partial * SCALE_C;
    __syncthreads();

    float s0 = sc[0], s1 = sc[1], s2 = sc[2], s3 = sc[3];
    float m = fmaxf(fmaxf(s0, s1), fmaxf(s2, s3));
    float e0 = expf(s0 - m), e1 = expf(s1 - m), e2 = expf(s2 - m), e3 = expf(s3 - m);
    float inv = 1.f / (e0 + e1 + e2 + e3);
    e0 *= inv; e1 *= inv; e2 *= inv; e3 *= inv;

    for (int c = threadIdx.x; c < Cc; c += 256) {
        float v = e0 * f[c] + e1 * f[Cc + c] + e2 * f[2 * Cc + c] + e3 * f[3 * Cc + c];
        dst[(size_t)bn * Cc + c] = row[c] + scale * v;
    }
}

// =====================================================================
// LayerNorm -> bf16 out. one block per row.
// =====================================================================
__global__ __launch_bounds__(256) void ln_ker(
    const float* __restrict__ in, const float* __restrict__ g,
    const float* __restrict__ bb, __hip_bfloat16* __restrict__ out)
{
    int row = blockIdx.x;
    __shared__ float buf[Cc];
    __shared__ float red[4];
    __shared__ float red2[4];
    const float* r = in + (size_t)row * Cc;
    int w = threadIdx.x >> 6, lane = threadIdx.x & 63;

    float s = 0.f;
    for (int c = threadIdx.x; c < Cc; c += 256) {
        float v = r[c];
        buf[c] = v;
        s += v;
    }
    #pragma unroll
    for (int o = 32; o; o >>= 1) s += __shfl_xor(s, o);
    if (lane == 0) red[w] = s;
    __syncthreads();
    float mean = (red[0] + red[1] + red[2] + red[3]) * (1.f / Cc);

    float vs = 0.f;
    for (int c = threadIdx.x; c < Cc; c += 256) {
        float d = buf[c] - mean;
        vs += d * d;
    }
    #pragma unroll
    for (int o = 32; o; o >>= 1) vs += __shfl_xor(vs, o);
    if (lane == 0) red2[w] = vs;
    __syncthreads();
    float var = (red2[0] + red2[1] + red2[2] + red2[3]) * (1.f / Cc);
    float inv = 1.f / sqrtf(var + 1e-6f);

    for (int c = threadIdx.x; c < Cc; c += 256)
        out[(size_t)row * Cc + c] =
            __float2bfloat16((buf[c] - mean) * inv * g[c] + bb[c]);
}

// =====================================================================
// Weight cast + transpose: W[K,N] fp32 -> WT[N,K] bf16.  32x32 LDS tiles.
// grid (N/32, K/32), block 256.
// =====================================================================
__global__ __launch_bounds__(256) void wcastT_ker(
    const float* __restrict__ W, __hip_bfloat16* __restrict__ WT,
    int K_, int N_)
{
    __shared__ float tile[32][33];
    int k0 = blockIdx.y * 32, n0 = blockIdx.x * 32;
    int t = threadIdx.x;
    int r = t >> 5, c = t & 31;
    #pragma unroll
    for (int p = 0; p < 4; ++p)
        tile[r + p * 8][c] = W[(size_t)(k0 + r + p * 8) * N_ + n0 + c];
    __syncthreads();
    #pragma unroll
    for (int p = 0; p < 4; ++p)
        WT[(size_t)(n0 + r + p * 8) * K_ + k0 + c] =
            __float2bfloat16(tile[c][r + p * 8]);
}

// =====================================================================
// bf16 MFMA GEMM: out[M,N] = A[M,K](bf16) @ BT[N,K](bf16)^T + bias (+epi)
// EPI 0: +bias   EPI 1: gelu(+bias)   EPI 2: +bias +res(fp32)
// 128x128 tile, BK=32, 256 threads (4 waves, 2x2), 4x4 16x16x32 frags/wave.
// global_load_lds(16B) staging, XOR k-unit swizzle (u ^= (row>>1)&3).
// =====================================================================
template <int EPI, typename OutT>
__global__ __launch_bounds__(256, 2) void gemm_bf16_ker(
    const __hip_bfloat16* __restrict__ A, const __hip_bfloat16* __restrict__ BT,
    const float* __restrict__ bias, const float* __restrict__ res,
    OutT* __restrict__ out, int M_, int N_, int K_)
{
    __shared__ short As[128 * 32];
    __shared__ short Bs[128 * 32];
    const int t = threadIdx.x;
    const int wid = t >> 6, lane = t & 63;
    const int row0 = blockIdx.y * 128, col0 = blockIdx.x * 128;
    const int wr = (wid >> 1) * 64, wc = (wid & 1) * 64;

    // ---- staging addresses (2 issues per matrix per thread) ----
    const int f0 = wid * 1024 + lane * 16;       // issue 0 flat byte
    const int f1 = f0 + 4096;                    // issue 1
    const int r0s = f0 >> 6, r1s = f1 >> 6;      // tile row (0..127)
    const int u0 = ((f0 >> 4) & 3) ^ ((r0s >> 1) & 3);
    const int u1 = ((f1 >> 4) & 3) ^ ((r1s >> 1) & 3);

    const __hip_bfloat16* aS0 = A + (size_t)(row0 + r0s) * K_ + u0 * 8;
    const __hip_bfloat16* aS1 = A + (size_t)(row0 + r1s) * K_ + u1 * 8;
    const __hip_bfloat16* bS0 = BT + (size_t)(col0 + r0s) * K_ + u0 * 8;
    const __hip_bfloat16* bS1 = BT + (size_t)(col0 + r1s) * K_ + u1 * 8;
    short* ldsA0 = As + (wid * 1024) / 2;
    short* ldsA1 = As + (4096 + wid * 1024) / 2;
    short* ldsB0 = Bs + (wid * 1024) / 2;
    short* ldsB1 = Bs + (4096 + wid * 1024) / 2;

    // ---- fragment read addresses ----
    const int fr = lane & 15;       // row within 16
    const int ku = lane >> 4;       // k-unit 0..3

    float4a acc[4][4];
    #pragma unroll
    for (int m = 0; m < 4; ++m)
        #pragma unroll
        for (int n = 0; n < 4; ++n)
            acc[m][n] = (float4a)0.f;

    for (int kt = 0; kt < K_; kt += 32) {
        gload16(aS0 + kt, ldsA0);
        gload16(aS1 + kt, ldsA1);
        gload16(bS0 + kt, ldsB0);
        gload16(bS1 + kt, ldsB1);
        __syncthreads();

        short8 af[4], bf[4];
        #pragma unroll
        for (int m = 0; m < 4; ++m) {
            int rl = wr + m * 16 + fr;
            int swz = ku ^ ((rl >> 1) & 3);
            af[m] = *(const short8*)(As + rl * 32 + swz * 8);
        }
        #pragma unroll
        for (int n = 0; n < 4; ++n) {
            int cl = wc + n * 16 + fr;
            int swz = ku ^ ((cl >> 1) & 3);
            bf[n] = *(const short8*)(Bs + cl * 32 + swz * 8);
        }
        #pragma unroll
        for (int m = 0; m < 4; ++m)
            #pragma unroll
            for (int n = 0; n < 4; ++n)
                acc[m][n] = __builtin_amdgcn_mfma_f32_16x16x32_bf16(
                    af[m], bf[n], acc[m][n], 0, 0, 0);
        __syncthreads();
    }

    // ---- epilogue: C/D layout col=lane&15, row=(lane>>4)*4+j ----
    const int fq = lane >> 4;
    #pragma unroll
    for (int m = 0; m < 4; ++m) {
        #pragma unroll
        for (int n = 0; n < 4; ++n) {
            int col = col0 + wc + n * 16 + fr;
            float b = bias[col];
            #pragma unroll
            for (int j = 0; j < 4; ++j) {
                int row = row0 + wr + m * 16 + fq * 4 + j;
                float v = acc[m][n][j] + b;
                if (EPI == 1) v = gelu_exact(v);
                if (EPI == 2) v += res[(size_t)row * N_ + col];
                store_val(out + (size_t)row * N_ + col, v);
            }
        }
    }
}

// =====================================================================
// Multi-head attention (fp32 math, bf16 in/out). block per (h, b).
// =====================================================================
__global__ __launch_bounds__(256) void attn_ker(
    const __hip_bfloat16* __restrict__ qkv, __hip_bfloat16* __restrict__ o)
{
    int h = blockIdx.x, b = blockIdx.y;
    __shared__ float Ks[Nc][65];
    const size_t rs = 3 * Cc;  // 2304
    const __hip_bfloat16* base = qkv + ((size_t)b * Nc) * rs + h * HDc;

    for (int idx = threadIdx.x; idx < Nc * HDc; idx += 256) {
        int j = idx >> 6, d = idx & 63;
        Ks[j][d] = __bfloat162float(base[(size_t)j * rs + Cc + d]);
    }
    __syncthreads();

    int w = threadIdx.x >> 6, lane = threadIdx.x & 63;
    int j3 = 192 + (lane & 3);

    for (int i = w; i < Nc; i += 4) {
        float qreg = __bfloat162float(base[(size_t)i * rs + lane]);
        float s0 = 0.f, s1 = 0.f, s2 = 0.f, s3 = 0.f;
        #pragma unroll 8
        for (int d = 0; d < 64; ++d) {
            float qd = __shfl(qreg, d);
            s0 += qd * Ks[lane][d];
            s1 += qd * Ks[64 + lane][d];
            s2 += qd * Ks[128 + lane][d];
            s3 += qd * Ks[j3][d];
        }
        s0 *= SCALE_H; s1 *= SCALE_H; s2 *= SCALE_H;
        s3 = (lane < 4) ? s3 * SCALE_H : -INFINITY;

        float m = fmaxf(fmaxf(s0, s1), fmaxf(s2, s3));
        #pragma unroll
        for (int off = 32; off; off >>= 1) m = fmaxf(m, __shfl_xor(m, off));
        float e0 = expf(s0 - m), e1 = expf(s1 - m), e2 = expf(s2 - m);
        float e3 = (lane < 4) ? expf(s3 - m) : 0.f;
        float sum = e0 + e1 + e2 + e3;
        #pragma unroll
        for (int off = 32; off; off >>= 1) sum += __shfl_xor(sum, off);
        float inv = 1.f / sum;
        e0 *= inv; e1 *= inv; e2 *= inv; e3 *= inv;

        const __hip_bfloat16* vbase = base + 2 * Cc + lane;
        float outv = 0.f;
        #pragma unroll 4
        for (int jj = 0; jj < 64; ++jj) {
            outv += __shfl(e0, jj) * __bfloat162float(vbase[(size_t)jj * rs]);
            outv += __shfl(e1, jj) * __bfloat162float(vbase[(size_t)(64 + jj) * rs]);
            outv += __shfl(e2, jj) * __bfloat162float(vbase[(size_t)(128 + jj) * rs]);
        }
        #pragma unroll
        for (int jj = 0; jj < 4; ++jj)
            outv += __shfl(e3, jj) * __bfloat162float(vbase[(size_t)(192 + jj) * rs]);

        o[((size_t)b * Nc + i) * Cc + h * HDc + lane] = __float2bfloat16(outv);
    }
}

// =====================================================================
extern "C" void kernel_launch(void* const* d_in, const int* in_sizes, int n_in,
                              void* d_out, int out_size, void* d_ws, size_t ws_size,
                              hipStream_t stream)
{
    const float* x       = (const float*)d_in[0];
    const float* y       = (const float*)d_in[1];
    const float* latents = (const float*)d_in[2];
    const float* scale_a = (const float*)d_in[3];
    const float* scale_v = (const float*)d_in[4];

    float* out = (float*)d_out;

    float* ws = (float*)d_ws;
    float* scores = ws;                                    // B*L*NCAT = 50176 f
    float* fusedb = scores + (size_t)Bc * Lc * NCAT;       // B*L*C = 98304 f
    __hip_bfloat16* tbuf = (__hip_bfloat16*)(fusedb + (size_t)Bc * Lc * Cc); // M*C bf16
    __hip_bfloat16* abuf = tbuf + (size_t)Mrows * Cc;      // M*C bf16
    __hip_bfloat16* big  = abuf + (size_t)Mrows * Cc;      // M*DFF bf16 (qkv-out / fc1-out)
    __hip_bfloat16* wT   = big + (size_t)Mrows * DFFc;     // 2 * 7,077,888 bf16

    // ---- latent bottleneck fusion ----
    lat_scores_ker<<<Bc * NCAT / 4, 256, 0, stream>>>(x, y, latents, scores);
    lat_fused_ker<<<dim3(Bc, 3), 256, 0, stream>>>(x, y, scores, fusedb);
    inject_ker<<<2 * Mrows, 256, 0, stream>>>(x, y, fusedb, scale_a, scale_v, out);

    // ---- per-stream ViT block ----
    for (int p = 0; p < 2; ++p) {
        int basei = 5 + 12 * p;
        const float* g1    = (const float*)d_in[basei + 0];
        const float* b1    = (const float*)d_in[basei + 1];
        const float* qkvw  = (const float*)d_in[basei + 2];
        const float* qkvb  = (const float*)d_in[basei + 3];
        const float* projw = (const float*)d_in[basei + 4];
        const float* projb = (const float*)d_in[basei + 5];
        const float* g2    = (const float*)d_in[basei + 6];
        const float* b2    = (const float*)d_in[basei + 7];
        const float* fc1w  = (const float*)d_in[basei + 8];
        const float* fc1b  = (const float*)d_in[basei + 9];
        const float* fc2w  = (const float*)d_in[basei + 10];
        const float* fc2b  = (const float*)d_in[basei + 11];

        __hip_bfloat16* wbase = wT + (size_t)p * 7077888;
        __hip_bfloat16* qkvT = wbase;                       // 2304*768
        __hip_bfloat16* projT = qkvT + 2304 * 768;          // 768*768
        __hip_bfloat16* fc1T  = projT + 768 * 768;          // 3072*768
        __hip_bfloat16* fc2T  = fc1T + 3072 * 768;          // 768*3072

        wcastT_ker<<<dim3(2304 / 32, 768 / 32), 256, 0, stream>>>(qkvw, qkvT, 768, 2304);
        wcastT_ker<<<dim3(768 / 32, 768 / 32), 256, 0, stream>>>(projw, projT, 768, 768);
        wcastT_ker<<<dim3(3072 / 32, 768 / 32), 256, 0, stream>>>(fc1w, fc1T, 768, 3072);
        wcastT_ker<<<dim3(768 / 32, 3072 / 32), 256, 0, stream>>>(fc2w, fc2T, 3072, 768);

        float* X = out + (size_t)p * Mrows * Cc;

        ln_ker<<<Mrows, 256, 0, stream>>>(X, g1, b1, tbuf);
        gemm_bf16_ker<0, __hip_bfloat16><<<dim3(2304 / 128, Mrows / 128), 256, 0, stream>>>(
            tbuf, qkvT, qkvb, nullptr, big, Mrows, 2304, 768);
        attn_ker<<<dim3(Hc, Bc), 256, 0, stream>>>(big, abuf);
        gemm_bf16_ker<2, float><<<dim3(768 / 128, Mrows / 128), 256, 0, stream>>>(
            abuf, projT, projb, X, X, Mrows, 768, 768);
        ln_ker<<<Mrows, 256, 0, stream>>>(X, g2, b2, tbuf);
        gemm_bf16_ker<1, __hip_bfloat16><<<dim3(3072 / 128, Mrows / 128), 256, 0, stream>>>(
            tbuf, fc1T, fc1b, nullptr, big, Mrows, 3072, 768);
        gemm_bf16_ker<2, float><<<dim3(768 / 128, Mrows / 128), 256, 0, stream>>>(
            big, fc2T, fc2b, X, X, Mrows, 768, 3072);
    }
}

// Round 3
// 602.810 us; speedup vs baseline: 6.5334x; 2.3745x over previous
//
#include <hip/hip_runtime.h>
#include <hip/hip_bf16.h>
#include <math.h>

// ---- problem constants ----
constexpr int Bc   = 32;
constexpr int Nc   = 196;
constexpr int Cc   = 768;
constexpr int Hc   = 12;
constexpr int HDc  = 64;
constexpr int Lc   = 4;
constexpr int DFFc = 3072;
constexpr int NCAT = 2 * Nc;          // 392
constexpr int Mrows = Bc * Nc;        // 6272
constexpr float SCALE_C = 0.03608439182435161f;  // 768^-0.5
constexpr float SCALE_H = 0.125f;                // 64^-0.5
constexpr float LOG2E   = 1.4426950408889634f;

typedef __attribute__((ext_vector_type(8))) short short8;
typedef __attribute__((ext_vector_type(4))) short s16x4;
typedef __attribute__((ext_vector_type(4))) float float4a;
typedef __attribute__((ext_vector_type(4))) _Float16 half4;

__device__ inline float gelu_exact(float v) {
    return 0.5f * v * (1.0f + erff(v * 0.7071067811865476f));
}

__device__ inline void store_val(float* p, float v) { *p = v; }
__device__ inline void store_val(__hip_bfloat16* p, float v) { *p = __float2bfloat16(v); }

__device__ inline void gload16(const void* g, void* l) {
    __builtin_amdgcn_global_load_lds(
        (const __attribute__((address_space(1))) void*)g,
        (__attribute__((address_space(3))) void*)l, 16, 0, 0);
}

// =====================================================================
// Latent scores: one WAVE per (b,j), all 4 latents at once.
// =====================================================================
__global__ __launch_bounds__(256) void lat_scores_ker(
    const float* __restrict__ x, const float* __restrict__ y,
    const float* __restrict__ lat, float* __restrict__ scores)
{
    int wglobal = blockIdx.x * 4 + (threadIdx.x >> 6);
    int lane = threadIdx.x & 63;
    int b = wglobal / NCAT, j = wglobal % NCAT;
    const float* row = (j < Nc) ? x + ((size_t)b * Nc + j) * Cc
                                : y + ((size_t)b * Nc + (j - Nc)) * Cc;
    float a0 = 0.f, a1 = 0.f, a2 = 0.f, a3 = 0.f;
    for (int c = lane; c < Cc; c += 64) {
        float rv = row[c];
        a0 += rv * lat[c];
        a1 += rv * lat[Cc + c];
        a2 += rv * lat[2 * Cc + c];
        a3 += rv * lat[3 * Cc + c];
    }
    #pragma unroll
    for (int o = 32; o; o >>= 1) {
        a0 += __shfl_xor(a0, o);
        a1 += __shfl_xor(a1, o);
        a2 += __shfl_xor(a2, o);
        a3 += __shfl_xor(a3, o);
    }
    if (lane == 0) {
        float* sb = scores + (size_t)b * Lc * NCAT + j;
        sb[0 * NCAT] = a0 * SCALE_C;
        sb[1 * NCAT] = a1 * SCALE_C;
        sb[2 * NCAT] = a2 * SCALE_C;
        sb[3 * NCAT] = a3 * SCALE_C;
    }
}

// =====================================================================
// softmax(scores) + fused = probs @ concat.  grid (B, 3).
// =====================================================================
__global__ __launch_bounds__(256) void lat_fused_ker(
    const float* __restrict__ x, const float* __restrict__ y,
    const float* __restrict__ scores, float* __restrict__ fused)
{
    int b = blockIdx.x, chunk = blockIdx.y;
    int t = threadIdx.x;
    __shared__ float p[Lc][NCAT];
    for (int idx = t; idx < Lc * NCAT; idx += 256)
        (&p[0][0])[idx] = scores[(size_t)b * Lc * NCAT + idx];
    __syncthreads();
    int w = t >> 6, lane = t & 63;
    {
        float m = -INFINITY;
        for (int j = lane; j < NCAT; j += 64) m = fmaxf(m, p[w][j]);
        #pragma unroll
        for (int o = 32; o; o >>= 1) m = fmaxf(m, __shfl_xor(m, o));
        float sum = 0.f;
        for (int j = lane; j < NCAT; j += 64) {
            float e = expf(p[w][j] - m);
            p[w][j] = e;
            sum += e;
        }
        #pragma unroll
        for (int o = 32; o; o >>= 1) sum += __shfl_xor(sum, o);
        float inv = 1.f / sum;
        for (int j = lane; j < NCAT; j += 64) p[w][j] *= inv;
    }
    __syncthreads();

    int c = chunk * 256 + t;
    float a0 = 0.f, a1 = 0.f, a2 = 0.f, a3 = 0.f;
    for (int j = 0; j < NCAT; ++j) {
        const float* row = (j < Nc) ? x + ((size_t)b * Nc + j) * Cc
                                    : y + ((size_t)b * Nc + (j - Nc)) * Cc;
        float rv = row[c];
        a0 += p[0][j] * rv;
        a1 += p[1][j] * rv;
        a2 += p[2][j] * rv;
        a3 += p[3][j] * rv;
    }
    float* fb = fused + (size_t)b * Lc * Cc + c;
    fb[0 * Cc] = a0; fb[1 * Cc] = a1; fb[2 * Cc] = a2; fb[3 * Cc] = a3;
}

// =====================================================================
// inject: out = src + scale * sdpa(src, fused, fused, C^-0.5)
// =====================================================================
__global__ __launch_bounds__(256) void inject_ker(
    const float* __restrict__ x, const float* __restrict__ y,
    const float* __restrict__ fused,
    const float* __restrict__ scale_a, const float* __restrict__ scale_v,
    float* __restrict__ out)
{
    int gid = blockIdx.x;
    int st = gid / Mrows;
    int bn = gid % Mrows;
    int b = bn / Nc;
    const float* src = st ? y : x;
    float scale = st ? scale_v[0] : scale_a[0];
    float* dst = out + (size_t)st * Mrows * Cc;
    const float* f = fused + (size_t)b * Lc * Cc;
    const float* row = src + (size_t)bn * Cc;

    __shared__ float sc[4];
    int w = threadIdx.x >> 6, lane = threadIdx.x & 63;
    float partial = 0.f;
    for (int c = lane; c < Cc; c += 64) partial += row[c] * f[w * Cc + c];
    #pragma unroll
    for (int o = 32; o; o >>= 1) partial += __shfl_xor(partial, o);
    if (lane == 0) sc[w] = partial * SCALE_C;
    __syncthreads();

    float s0 = sc[0], s1 = sc[1], s2 = sc[2], s3 = sc[3];
    float m = fmaxf(fmaxf(s0, s1), fmaxf(s2, s3));
    float e0 = expf(s0 - m), e1 = expf(s1 - m), e2 = expf(s2 - m), e3 = expf(s3 - m);
    float inv = 1.f / (e0 + e1 + e2 + e3);
    e0 *= inv; e1 *= inv; e2 *= inv; e3 *= inv;

    for (int c = threadIdx.x; c < Cc; c += 256) {
        float v = e0 * f[c] + e1 * f[Cc + c] + e2 * f[2 * Cc + c] + e3 * f[3 * Cc + c];
        dst[(size_t)bn * Cc + c] = row[c] + scale * v;
    }
}

// =====================================================================
// LayerNorm -> bf16 out. one block per row.
// =====================================================================
__global__ __launch_bounds__(256) void ln_ker(
    const float* __restrict__ in, const float* __restrict__ g,
    const float* __restrict__ bb, __hip_bfloat16* __restrict__ out)
{
    int row = blockIdx.x;
    __shared__ float buf[Cc];
    __shared__ float red[4];
    __shared__ float red2[4];
    const float* r = in + (size_t)row * Cc;
    int w = threadIdx.x >> 6, lane = threadIdx.x & 63;

    float s = 0.f;
    for (int c = threadIdx.x; c < Cc; c += 256) {
        float v = r[c];
        buf[c] = v;
        s += v;
    }
    #pragma unroll
    for (int o = 32; o; o >>= 1) s += __shfl_xor(s, o);
    if (lane == 0) red[w] = s;
    __syncthreads();
    float mean = (red[0] + red[1] + red[2] + red[3]) * (1.f / Cc);

    float vs = 0.f;
    for (int c = threadIdx.x; c < Cc; c += 256) {
        float d = buf[c] - mean;
        vs += d * d;
    }
    #pragma unroll
    for (int o = 32; o; o >>= 1) vs += __shfl_xor(vs, o);
    if (lane == 0) red2[w] = vs;
    __syncthreads();
    float var = (red2[0] + red2[1] + red2[2] + red2[3]) * (1.f / Cc);
    float inv = 1.f / sqrtf(var + 1e-6f);

    for (int c = threadIdx.x; c < Cc; c += 256)
        out[(size_t)row * Cc + c] =
            __float2bfloat16((buf[c] - mean) * inv * g[c] + bb[c]);
}

// =====================================================================
// Weight cast + transpose: W[K,N] fp32 -> WT[N,K] bf16.
// =====================================================================
__global__ __launch_bounds__(256) void wcastT_ker(
    const float* __restrict__ W, __hip_bfloat16* __restrict__ WT,
    int K_, int N_)
{
    __shared__ float tile[32][33];
    int k0 = blockIdx.y * 32, n0 = blockIdx.x * 32;
    int t = threadIdx.x;
    int r = t >> 5, c = t & 31;
    #pragma unroll
    for (int p = 0; p < 4; ++p)
        tile[r + p * 8][c] = W[(size_t)(k0 + r + p * 8) * N_ + n0 + c];
    __syncthreads();
    #pragma unroll
    for (int p = 0; p < 4; ++p)
        WT[(size_t)(n0 + r + p * 8) * K_ + k0 + c] =
            __float2bfloat16(tile[c][r + p * 8]);
}

// =====================================================================
// bf16 MFMA GEMM (unchanged from round 2).
// =====================================================================
template <int EPI, typename OutT>
__global__ __launch_bounds__(256, 2) void gemm_bf16_ker(
    const __hip_bfloat16* __restrict__ A, const __hip_bfloat16* __restrict__ BT,
    const float* __restrict__ bias, const float* __restrict__ res,
    OutT* __restrict__ out, int M_, int N_, int K_)
{
    __shared__ short As[128 * 32];
    __shared__ short Bs[128 * 32];
    const int t = threadIdx.x;
    const int wid = t >> 6, lane = t & 63;
    const int row0 = blockIdx.y * 128, col0 = blockIdx.x * 128;
    const int wr = (wid >> 1) * 64, wc = (wid & 1) * 64;

    const int f0 = wid * 1024 + lane * 16;
    const int f1 = f0 + 4096;
    const int r0s = f0 >> 6, r1s = f1 >> 6;
    const int u0 = ((f0 >> 4) & 3) ^ ((r0s >> 1) & 3);
    const int u1 = ((f1 >> 4) & 3) ^ ((r1s >> 1) & 3);

    const __hip_bfloat16* aS0 = A + (size_t)(row0 + r0s) * K_ + u0 * 8;
    const __hip_bfloat16* aS1 = A + (size_t)(row0 + r1s) * K_ + u1 * 8;
    const __hip_bfloat16* bS0 = BT + (size_t)(col0 + r0s) * K_ + u0 * 8;
    const __hip_bfloat16* bS1 = BT + (size_t)(col0 + r1s) * K_ + u1 * 8;
    short* ldsA0 = As + (wid * 1024) / 2;
    short* ldsA1 = As + (4096 + wid * 1024) / 2;
    short* ldsB0 = Bs + (wid * 1024) / 2;
    short* ldsB1 = Bs + (4096 + wid * 1024) / 2;

    const int fr = lane & 15;
    const int ku = lane >> 4;

    float4a acc[4][4];
    #pragma unroll
    for (int m = 0; m < 4; ++m)
        #pragma unroll
        for (int n = 0; n < 4; ++n)
            acc[m][n] = (float4a)0.f;

    for (int kt = 0; kt < K_; kt += 32) {
        gload16(aS0 + kt, ldsA0);
        gload16(aS1 + kt, ldsA1);
        gload16(bS0 + kt, ldsB0);
        gload16(bS1 + kt, ldsB1);
        __syncthreads();

        short8 af[4], bf[4];
        #pragma unroll
        for (int m = 0; m < 4; ++m) {
            int rl = wr + m * 16 + fr;
            int swz = ku ^ ((rl >> 1) & 3);
            af[m] = *(const short8*)(As + rl * 32 + swz * 8);
        }
        #pragma unroll
        for (int n = 0; n < 4; ++n) {
            int cl = wc + n * 16 + fr;
            int swz = ku ^ ((cl >> 1) & 3);
            bf[n] = *(const short8*)(Bs + cl * 32 + swz * 8);
        }
        #pragma unroll
        for (int m = 0; m < 4; ++m)
            #pragma unroll
            for (int n = 0; n < 4; ++n)
                acc[m][n] = __builtin_amdgcn_mfma_f32_16x16x32_bf16(
                    af[m], bf[n], acc[m][n], 0, 0, 0);
        __syncthreads();
    }

    const int fq = lane >> 4;
    #pragma unroll
    for (int m = 0; m < 4; ++m) {
        #pragma unroll
        for (int n = 0; n < 4; ++n) {
            int col = col0 + wc + n * 16 + fr;
            float b = bias[col];
            #pragma unroll
            for (int j = 0; j < 4; ++j) {
                int row = row0 + wr + m * 16 + fq * 4 + j;
                float v = acc[m][n][j] + b;
                if (EPI == 1) v = gelu_exact(v);
                if (EPI == 2) v += res[(size_t)row * N_ + col];
                store_val(out + (size_t)row * N_ + col, v);
            }
        }
    }
}

// =====================================================================
// MFMA attention. Block per (h,b), 4 waves; wave owns query tiles
// qt = w, w+4, ... (13 tiles of 16 q, padded to 208).
// S^T = mfma_16x16x32_bf16(A=K, B=Q) -> col=query (lane&15).
// Softmax: 52 lane-local scores + shfl_xor(16,32).
// PV: O^T = mfma_16x16x16f16(A=V^T from LDS, B=P direct from regs).
// K in LDS bf16 XOR-unit-swizzled; V^T in LDS f16 [64][216].
// =====================================================================
constexpr int NKT = 13;          // key tiles (208 padded keys)
constexpr int NQT = 13;          // query tiles
constexpr int NPAD = NKT * 16;   // 208
constexpr int VTS = 216;         // V^T row stride (f16)

__global__ __launch_bounds__(256) void attn_mfma_ker(
    const __hip_bfloat16* __restrict__ qkv, __hip_bfloat16* __restrict__ o)
{
    int h = blockIdx.x, b = blockIdx.y;
    __shared__ short Ks[NPAD * 64];        // bf16 bits, swizzled 16B units
    __shared__ _Float16 VT[64 * VTS];      // V transposed, f16
    const size_t rs = 3 * Cc;              // 2304
    const __hip_bfloat16* base = qkv + (size_t)b * Nc * rs + h * HDc;
    const int t = threadIdx.x;

    // ---- stage K (swizzled) + V^T ----
    for (int c = t; c < NPAD * 8; c += 256) {
        int row = c >> 3, u = c & 7;
        int srow = row < Nc ? row : Nc - 1;   // clamp padding (finite vals)
        short8 kv = *(const short8*)(base + (size_t)srow * rs + Cc + u * 8);
        *(short8*)(Ks + row * 64 + ((u ^ (row & 7)) << 3)) = kv;
        short8 vv = *(const short8*)(base + (size_t)srow * rs + 2 * Cc + u * 8);
        #pragma unroll
        for (int w = 0; w < 8; ++w) {
            __hip_bfloat16 bv = ((const __hip_bfloat16*)&vv)[w];
            VT[(u * 8 + w) * VTS + row] = (_Float16)__bfloat162float(bv);
        }
    }
    __syncthreads();

    const int wv = t >> 6, lane = t & 63;
    const int g = lane >> 4, c16 = lane & 15;
    const float KS = SCALE_H * LOG2E;

    for (int qt = wv; qt < NQT; qt += 4) {
        // ---- Q B-fragments (2 k-slices) from global ----
        int qrow = qt * 16 + c16;
        int sq = qrow < Nc ? qrow : Nc - 1;
        const __hip_bfloat16* qb = base + (size_t)sq * rs + g * 8;
        short8 bq0 = *(const short8*)(qb);
        short8 bq1 = *(const short8*)(qb + 32);

        // ---- S^T = K @ Q^T ----
        float4a acc[NKT];
        #pragma unroll
        for (int kt = 0; kt < NKT; ++kt) acc[kt] = (float4a)0.f;
        #pragma unroll
        for (int kt = 0; kt < NKT; ++kt) {
            int r = kt * 16 + c16;
            short8 a0 = *(const short8*)(Ks + r * 64 + ((g ^ (r & 7)) << 3));
            short8 a1 = *(const short8*)(Ks + r * 64 + (((4 + g) ^ (r & 7)) << 3));
            acc[kt] = __builtin_amdgcn_mfma_f32_16x16x32_bf16(a0, bq0, acc[kt], 0, 0, 0);
            acc[kt] = __builtin_amdgcn_mfma_f32_16x16x32_bf16(a1, bq1, acc[kt], 0, 0, 0);
        }

        // ---- masked softmax per query (col) ----
        float m = -INFINITY;
        #pragma unroll
        for (int kt = 0; kt < NKT; ++kt) {
            #pragma unroll
            for (int j = 0; j < 4; ++j) {
                int key = kt * 16 + g * 4 + j;
                float v = (key < Nc) ? acc[kt][j] * KS : -INFINITY;
                acc[kt][j] = v;
                m = fmaxf(m, v);
            }
        }
        m = fmaxf(m, __shfl_xor(m, 16));
        m = fmaxf(m, __shfl_xor(m, 32));

        float sum = 0.f;
        half4 pb[NKT];
        #pragma unroll
        for (int kt = 0; kt < NKT; ++kt) {
            #pragma unroll
            for (int j = 0; j < 4; ++j) {
                float e = exp2f(acc[kt][j] - m);   // exp2(-inf)=0 kills pads
                sum += e;
                pb[kt][j] = (_Float16)e;
            }
        }
        sum += __shfl_xor(sum, 16);
        sum += __shfl_xor(sum, 32);
        float inv = 1.f / sum;

        // ---- O^T = V^T @ P  (P direct from regs as B-operand) ----
        float4a oa[4];
        #pragma unroll
        for (int dt = 0; dt < 4; ++dt) oa[dt] = (float4a)0.f;
        #pragma unroll
        for (int kt = 0; kt < NKT; ++kt) {
            #pragma unroll
            for (int dt = 0; dt < 4; ++dt) {
                half4 av = *(const half4*)(VT + (size_t)(dt * 16 + c16) * VTS
                                              + kt * 16 + g * 4);
                oa[dt] = __builtin_amdgcn_mfma_f32_16x16x16f16(av, pb[kt], oa[dt], 0, 0, 0);
            }
        }

        // ---- store O (col=query, rows=d) ----
        if (qrow < Nc) {
            __hip_bfloat16* ob = o + ((size_t)b * Nc + qrow) * Cc + h * HDc;
            #pragma unroll
            for (int dt = 0; dt < 4; ++dt) {
                __hip_bfloat16 tmp[4];
                #pragma unroll
                for (int j = 0; j < 4; ++j)
                    tmp[j] = __float2bfloat16(oa[dt][j] * inv);
                *(s16x4*)(ob + dt * 16 + g * 4) = *(const s16x4*)tmp;
            }
        }
    }
}

// =====================================================================
extern "C" void kernel_launch(void* const* d_in, const int* in_sizes, int n_in,
                              void* d_out, int out_size, void* d_ws, size_t ws_size,
                              hipStream_t stream)
{
    const float* x       = (const float*)d_in[0];
    const float* y       = (const float*)d_in[1];
    const float* latents = (const float*)d_in[2];
    const float* scale_a = (const float*)d_in[3];
    const float* scale_v = (const float*)d_in[4];

    float* out = (float*)d_out;

    float* ws = (float*)d_ws;
    float* scores = ws;                                    // B*L*NCAT
    float* fusedb = scores + (size_t)Bc * Lc * NCAT;       // B*L*C
    __hip_bfloat16* tbuf = (__hip_bfloat16*)(fusedb + (size_t)Bc * Lc * Cc);
    __hip_bfloat16* abuf = tbuf + (size_t)Mrows * Cc;
    __hip_bfloat16* big  = abuf + (size_t)Mrows * Cc;
    __hip_bfloat16* wT   = big + (size_t)Mrows * DFFc;

    lat_scores_ker<<<Bc * NCAT / 4, 256, 0, stream>>>(x, y, latents, scores);
    lat_fused_ker<<<dim3(Bc, 3), 256, 0, stream>>>(x, y, scores, fusedb);
    inject_ker<<<2 * Mrows, 256, 0, stream>>>(x, y, fusedb, scale_a, scale_v, out);

    for (int p = 0; p < 2; ++p) {
        int basei = 5 + 12 * p;
        const float* g1    = (const float*)d_in[basei + 0];
        const float* b1    = (const float*)d_in[basei + 1];
        const float* qkvw  = (const float*)d_in[basei + 2];
        const float* qkvb  = (const float*)d_in[basei + 3];
        const float* projw = (const float*)d_in[basei + 4];
        const float* projb = (const float*)d_in[basei + 5];
        const float* g2    = (const float*)d_in[basei + 6];
        const float* b2    = (const float*)d_in[basei + 7];
        const float* fc1w  = (const float*)d_in[basei + 8];
        const float* fc1b  = (const float*)d_in[basei + 9];
        const float* fc2w  = (const float*)d_in[basei + 10];
        const float* fc2b  = (const float*)d_in[basei + 11];

        __hip_bfloat16* wbase = wT + (size_t)p * 7077888;
        __hip_bfloat16* qkvT = wbase;
        __hip_bfloat16* projT = qkvT + 2304 * 768;
        __hip_bfloat16* fc1T  = projT + 768 * 768;
        __hip_bfloat16* fc2T  = fc1T + 3072 * 768;

        wcastT_ker<<<dim3(2304 / 32, 768 / 32), 256, 0, stream>>>(qkvw, qkvT, 768, 2304);
        wcastT_ker<<<dim3(768 / 32, 768 / 32), 256, 0, stream>>>(projw, projT, 768, 768);
        wcastT_ker<<<dim3(3072 / 32, 768 / 32), 256, 0, stream>>>(fc1w, fc1T, 768, 3072);
        wcastT_ker<<<dim3(768 / 32, 3072 / 32), 256, 0, stream>>>(fc2w, fc2T, 3072, 768);

        float* X = out + (size_t)p * Mrows * Cc;

        ln_ker<<<Mrows, 256, 0, stream>>>(X, g1, b1, tbuf);
        gemm_bf16_ker<0, __hip_bfloat16><<<dim3(2304 / 128, Mrows / 128), 256, 0, stream>>>(
            tbuf, qkvT, qkvb, nullptr, big, Mrows, 2304, 768);
        attn_mfma_ker<<<dim3(Hc, Bc), 256, 0, stream>>>(big, abuf);
        gemm_bf16_ker<2, float><<<dim3(768 / 128, Mrows / 128), 256, 0, stream>>>(
            abuf, projT, projb, X, X, Mrows, 768, 768);
        ln_ker<<<Mrows, 256, 0, stream>>>(X, g2, b2, tbuf);
        gemm_bf16_ker<1, __hip_bfloat16><<<dim3(3072 / 128, Mrows / 128), 256, 0, stream>>>(
            tbuf, fc1T, fc1b, nullptr, big, Mrows, 3072, 768);
        gemm_bf16_ker<2, float><<<dim3(768 / 128, Mrows / 128), 256, 0, stream>>>(
            big, fc2T, fc2b, X, X, Mrows, 768, 3072);
    }
}

// Round 4
// 491.820 us; speedup vs baseline: 8.0078x; 1.2257x over previous
//
#include <hip/hip_runtime.h>
#include <hip/hip_bf16.h>
#include <math.h>

// ---- problem constants ----
constexpr int Bc   = 32;
constexpr int Nc   = 196;
constexpr int Cc   = 768;
constexpr int Hc   = 12;
constexpr int HDc  = 64;
constexpr int Lc   = 4;
constexpr int DFFc = 3072;
constexpr int NCAT = 2 * Nc;          // 392
constexpr int Mrows = Bc * Nc;        // 6272
constexpr float SCALE_C = 0.03608439182435161f;  // 768^-0.5
constexpr float SCALE_H = 0.125f;                // 64^-0.5
constexpr float LOG2E   = 1.4426950408889634f;

typedef __attribute__((ext_vector_type(8))) short short8;
typedef __attribute__((ext_vector_type(4))) short s16x4;
typedef __attribute__((ext_vector_type(4))) float float4a;
typedef __attribute__((ext_vector_type(4))) _Float16 half4;

__device__ inline float gelu_exact(float v) {
    return 0.5f * v * (1.0f + erff(v * 0.7071067811865476f));
}

__device__ inline void store_val(float* p, float v) { *p = v; }
__device__ inline void store_val(__hip_bfloat16* p, float v) { *p = __float2bfloat16(v); }

__device__ inline void gload16(const void* g, void* l) {
    __builtin_amdgcn_global_load_lds(
        (const __attribute__((address_space(1))) void*)g,
        (__attribute__((address_space(3))) void*)l, 16, 0, 0);
}

// =====================================================================
// Latent scores: one WAVE per (b,j), all 4 latents at once.
// =====================================================================
__global__ __launch_bounds__(256) void lat_scores_ker(
    const float* __restrict__ x, const float* __restrict__ y,
    const float* __restrict__ lat, float* __restrict__ scores)
{
    int wglobal = blockIdx.x * 4 + (threadIdx.x >> 6);
    int lane = threadIdx.x & 63;
    int b = wglobal / NCAT, j = wglobal % NCAT;
    const float* row = (j < Nc) ? x + ((size_t)b * Nc + j) * Cc
                                : y + ((size_t)b * Nc + (j - Nc)) * Cc;
    float a0 = 0.f, a1 = 0.f, a2 = 0.f, a3 = 0.f;
    for (int c = lane; c < Cc; c += 64) {
        float rv = row[c];
        a0 += rv * lat[c];
        a1 += rv * lat[Cc + c];
        a2 += rv * lat[2 * Cc + c];
        a3 += rv * lat[3 * Cc + c];
    }
    #pragma unroll
    for (int o = 32; o; o >>= 1) {
        a0 += __shfl_xor(a0, o);
        a1 += __shfl_xor(a1, o);
        a2 += __shfl_xor(a2, o);
        a3 += __shfl_xor(a3, o);
    }
    if (lane == 0) {
        float* sb = scores + (size_t)b * Lc * NCAT + j;
        sb[0 * NCAT] = a0 * SCALE_C;
        sb[1 * NCAT] = a1 * SCALE_C;
        sb[2 * NCAT] = a2 * SCALE_C;
        sb[3 * NCAT] = a3 * SCALE_C;
    }
}

// =====================================================================
// In-place softmax of scores rows. grid Bc, wave w -> latent row w.
// =====================================================================
__global__ __launch_bounds__(256) void lat_softmax_ker(float* __restrict__ scores)
{
    int b = blockIdx.x;
    int w = threadIdx.x >> 6, lane = threadIdx.x & 63;
    float* row = scores + (size_t)b * Lc * NCAT + w * NCAT;
    float m = -INFINITY;
    for (int j = lane; j < NCAT; j += 64) m = fmaxf(m, row[j]);
    #pragma unroll
    for (int o = 32; o; o >>= 1) m = fmaxf(m, __shfl_xor(m, o));
    float sum = 0.f;
    float e0 = expf(row[lane] - m);
    float e1 = expf(row[lane + 64] - m);
    float e2 = expf(row[lane + 128] - m);
    float e3 = expf(row[lane + 192] - m);
    float e4 = expf(row[lane + 256] - m);
    float e5 = expf(row[lane + 320] - m);
    float e6 = (lane < 8) ? expf(row[lane + 384] - m) : 0.f;
    sum = e0 + e1 + e2 + e3 + e4 + e5 + e6;
    #pragma unroll
    for (int o = 32; o; o >>= 1) sum += __shfl_xor(sum, o);
    float inv = 1.f / sum;
    row[lane] = e0 * inv;
    row[lane + 64] = e1 * inv;
    row[lane + 128] = e2 * inv;
    row[lane + 192] = e3 * inv;
    row[lane + 256] = e4 * inv;
    row[lane + 320] = e5 * inv;
    if (lane < 8) row[lane + 384] = e6 * inv;
}

// =====================================================================
// fused = probs @ concat.  grid (Bc, 12): 64-col chunk; t>>6 = latent.
// =====================================================================
__global__ __launch_bounds__(256) void lat_fused_ker(
    const float* __restrict__ x, const float* __restrict__ y,
    const float* __restrict__ probs, float* __restrict__ fused)
{
    int b = blockIdx.x, chunk = blockIdx.y;
    int t = threadIdx.x;
    int l = t >> 6;
    int c = chunk * 64 + (t & 63);
    __shared__ float p[Lc][NCAT];
    for (int idx = t; idx < Lc * NCAT; idx += 256)
        (&p[0][0])[idx] = probs[(size_t)b * Lc * NCAT + idx];
    __syncthreads();

    float acc0 = 0.f, acc1 = 0.f;
    for (int j = 0; j < Nc; j += 2) {
        const float* r0 = x + ((size_t)b * Nc + j) * Cc;
        acc0 += p[l][j] * r0[c];
        acc1 += p[l][j + 1] * r0[Cc + c];
    }
    for (int j = 0; j < Nc; j += 2) {
        const float* r0 = y + ((size_t)b * Nc + j) * Cc;
        acc0 += p[l][Nc + j] * r0[c];
        acc1 += p[l][Nc + j + 1] * r0[Cc + c];
    }
    fused[(size_t)b * Lc * Cc + l * Cc + c] = acc0 + acc1;
}

// =====================================================================
// inject: out = src + scale * sdpa(src, fused, fused, C^-0.5)
// =====================================================================
__global__ __launch_bounds__(256) void inject_ker(
    const float* __restrict__ x, const float* __restrict__ y,
    const float* __restrict__ fused,
    const float* __restrict__ scale_a, const float* __restrict__ scale_v,
    float* __restrict__ out)
{
    int gid = blockIdx.x;
    int st = gid / Mrows;
    int bn = gid % Mrows;
    int b = bn / Nc;
    const float* src = st ? y : x;
    float scale = st ? scale_v[0] : scale_a[0];
    float* dst = out + (size_t)st * Mrows * Cc;
    const float* f = fused + (size_t)b * Lc * Cc;
    const float* row = src + (size_t)bn * Cc;

    __shared__ float sc[4];
    int w = threadIdx.x >> 6, lane = threadIdx.x & 63;
    float partial = 0.f;
    for (int c = lane; c < Cc; c += 64) partial += row[c] * f[w * Cc + c];
    #pragma unroll
    for (int o = 32; o; o >>= 1) partial += __shfl_xor(partial, o);
    if (lane == 0) sc[w] = partial * SCALE_C;
    __syncthreads();

    float s0 = sc[0], s1 = sc[1], s2 = sc[2], s3 = sc[3];
    float m = fmaxf(fmaxf(s0, s1), fmaxf(s2, s3));
    float e0 = expf(s0 - m), e1 = expf(s1 - m), e2 = expf(s2 - m), e3 = expf(s3 - m);
    float inv = 1.f / (e0 + e1 + e2 + e3);
    e0 *= inv; e1 *= inv; e2 *= inv; e3 *= inv;

    for (int c = threadIdx.x; c < Cc; c += 256) {
        float v = e0 * f[c] + e1 * f[Cc + c] + e2 * f[2 * Cc + c] + e3 * f[3 * Cc + c];
        dst[(size_t)bn * Cc + c] = row[c] + scale * v;
    }
}

// =====================================================================
// LayerNorm -> bf16. z-batched: one block per (row, stream).
// =====================================================================
__global__ __launch_bounds__(256) void ln_ker(
    const float* __restrict__ in, size_t inz,
    const float* __restrict__ g0, const float* __restrict__ b0,
    const float* __restrict__ g1, const float* __restrict__ b1,
    __hip_bfloat16* __restrict__ out, size_t outz)
{
    int z = blockIdx.z;
    const float* g = z ? g1 : g0;
    const float* bb = z ? b1 : b0;
    in += (size_t)z * inz; out += (size_t)z * outz;

    int row = blockIdx.x;
    __shared__ float buf[Cc];
    __shared__ float red[4];
    __shared__ float red2[4];
    const float* r = in + (size_t)row * Cc;
    int w = threadIdx.x >> 6, lane = threadIdx.x & 63;

    float s = 0.f;
    for (int c = threadIdx.x; c < Cc; c += 256) {
        float v = r[c];
        buf[c] = v;
        s += v;
    }
    #pragma unroll
    for (int o = 32; o; o >>= 1) s += __shfl_xor(s, o);
    if (lane == 0) red[w] = s;
    __syncthreads();
    float mean = (red[0] + red[1] + red[2] + red[3]) * (1.f / Cc);

    float vs = 0.f;
    for (int c = threadIdx.x; c < Cc; c += 256) {
        float d = buf[c] - mean;
        vs += d * d;
    }
    #pragma unroll
    for (int o = 32; o; o >>= 1) vs += __shfl_xor(vs, o);
    if (lane == 0) red2[w] = vs;
    __syncthreads();
    float var = (red2[0] + red2[1] + red2[2] + red2[3]) * (1.f / Cc);
    float inv = 1.f / sqrtf(var + 1e-6f);

    for (int c = threadIdx.x; c < Cc; c += 256)
        out[(size_t)row * Cc + c] =
            __float2bfloat16((buf[c] - mean) * inv * g[c] + bb[c]);
}

// =====================================================================
// All 8 weight transposes in one dispatch. grid (6912, 1, 2).
// tile ranges: qkv[0,1728) proj[1728,2304) fc1[2304,4608) fc2[4608,6912)
// =====================================================================
struct WArgs {
    const float* src[8];
    __hip_bfloat16* dst[8];
};

__global__ __launch_bounds__(256) void wcast_all_ker(WArgs wa)
{
    int z = blockIdx.z;
    int bx = blockIdx.x;
    int which, tile, K_, N_;
    if (bx < 1728)      { which = 0; tile = bx;        K_ = 768;  N_ = 2304; }
    else if (bx < 2304) { which = 1; tile = bx - 1728; K_ = 768;  N_ = 768;  }
    else if (bx < 4608) { which = 2; tile = bx - 2304; K_ = 768;  N_ = 3072; }
    else                { which = 3; tile = bx - 4608; K_ = 3072; N_ = 768;  }
    const float* W = wa.src[z * 4 + which];
    __hip_bfloat16* WT = wa.dst[z * 4 + which];
    int ntx = N_ >> 5;
    int n0 = (tile % ntx) * 32, k0 = (tile / ntx) * 32;

    __shared__ float tilebuf[32][33];
    int t = threadIdx.x;
    int r = t >> 5, c = t & 31;
    #pragma unroll
    for (int p = 0; p < 4; ++p)
        tilebuf[r + p * 8][c] = W[(size_t)(k0 + r + p * 8) * N_ + n0 + c];
    __syncthreads();
    #pragma unroll
    for (int p = 0; p < 4; ++p)
        WT[(size_t)(n0 + r + p * 8) * K_ + k0 + c] =
            __float2bfloat16(tilebuf[c][r + p * 8]);
}

// =====================================================================
// bf16 MFMA GEMM, z-batched.
// =====================================================================
template <int EPI, typename OutT>
__global__ __launch_bounds__(256, 2) void gemm_bf16_ker(
    const __hip_bfloat16* __restrict__ A, size_t Az,
    const __hip_bfloat16* __restrict__ BT, size_t BTz,
    const float* __restrict__ bias0, const float* __restrict__ bias1,
    const float* __restrict__ res, size_t resz,
    OutT* __restrict__ out, size_t outz,
    int M_, int N_, int K_)
{
    const int z = blockIdx.z;
    A += (size_t)z * Az;
    BT += (size_t)z * BTz;
    const float* bias = z ? bias1 : bias0;
    res += (size_t)z * resz;
    out += (size_t)z * outz;

    __shared__ short As[128 * 32];
    __shared__ short Bs[128 * 32];
    const int t = threadIdx.x;
    const int wid = t >> 6, lane = t & 63;
    const int row0 = blockIdx.y * 128, col0 = blockIdx.x * 128;
    const int wr = (wid >> 1) * 64, wc = (wid & 1) * 64;

    const int f0 = wid * 1024 + lane * 16;
    const int f1 = f0 + 4096;
    const int r0s = f0 >> 6, r1s = f1 >> 6;
    const int u0 = ((f0 >> 4) & 3) ^ ((r0s >> 1) & 3);
    const int u1 = ((f1 >> 4) & 3) ^ ((r1s >> 1) & 3);

    const __hip_bfloat16* aS0 = A + (size_t)(row0 + r0s) * K_ + u0 * 8;
    const __hip_bfloat16* aS1 = A + (size_t)(row0 + r1s) * K_ + u1 * 8;
    const __hip_bfloat16* bS0 = BT + (size_t)(col0 + r0s) * K_ + u0 * 8;
    const __hip_bfloat16* bS1 = BT + (size_t)(col0 + r1s) * K_ + u1 * 8;
    short* ldsA0 = As + (wid * 1024) / 2;
    short* ldsA1 = As + (4096 + wid * 1024) / 2;
    short* ldsB0 = Bs + (wid * 1024) / 2;
    short* ldsB1 = Bs + (4096 + wid * 1024) / 2;

    const int fr = lane & 15;
    const int ku = lane >> 4;

    float4a acc[4][4];
    #pragma unroll
    for (int m = 0; m < 4; ++m)
        #pragma unroll
        for (int n = 0; n < 4; ++n)
            acc[m][n] = (float4a)0.f;

    for (int kt = 0; kt < K_; kt += 32) {
        gload16(aS0 + kt, ldsA0);
        gload16(aS1 + kt, ldsA1);
        gload16(bS0 + kt, ldsB0);
        gload16(bS1 + kt, ldsB1);
        __syncthreads();

        short8 af[4], bf[4];
        #pragma unroll
        for (int m = 0; m < 4; ++m) {
            int rl = wr + m * 16 + fr;
            int swz = ku ^ ((rl >> 1) & 3);
            af[m] = *(const short8*)(As + rl * 32 + swz * 8);
        }
        #pragma unroll
        for (int n = 0; n < 4; ++n) {
            int cl = wc + n * 16 + fr;
            int swz = ku ^ ((cl >> 1) & 3);
            bf[n] = *(const short8*)(Bs + cl * 32 + swz * 8);
        }
        #pragma unroll
        for (int m = 0; m < 4; ++m)
            #pragma unroll
            for (int n = 0; n < 4; ++n)
                acc[m][n] = __builtin_amdgcn_mfma_f32_16x16x32_bf16(
                    af[m], bf[n], acc[m][n], 0, 0, 0);
        __syncthreads();
    }

    const int fq = lane >> 4;
    #pragma unroll
    for (int m = 0; m < 4; ++m) {
        #pragma unroll
        for (int n = 0; n < 4; ++n) {
            int col = col0 + wc + n * 16 + fr;
            float b = bias[col];
            #pragma unroll
            for (int j = 0; j < 4; ++j) {
                int row = row0 + wr + m * 16 + fq * 4 + j;
                float v = acc[m][n][j] + b;
                if (EPI == 1) v = gelu_exact(v);
                if (EPI == 2) v += res[(size_t)row * N_ + col];
                store_val(out + (size_t)row * N_ + col, v);
            }
        }
    }
}

// =====================================================================
// MFMA attention, z-batched. Block per (h, b, z).
// =====================================================================
constexpr int NKT = 13;
constexpr int NQT = 13;
constexpr int NPAD = NKT * 16;   // 208
constexpr int VTS = 216;

__global__ __launch_bounds__(256) void attn_mfma_ker(
    const __hip_bfloat16* __restrict__ qkv, size_t qz,
    __hip_bfloat16* __restrict__ o, size_t oz)
{
    int z = blockIdx.z;
    qkv += (size_t)z * qz;
    o += (size_t)z * oz;

    int h = blockIdx.x, b = blockIdx.y;
    __shared__ short Ks[NPAD * 64];
    __shared__ _Float16 VT[64 * VTS];
    const size_t rs = 3 * Cc;
    const __hip_bfloat16* base = qkv + (size_t)b * Nc * rs + h * HDc;
    const int t = threadIdx.x;

    for (int c = t; c < NPAD * 8; c += 256) {
        int row = c >> 3, u = c & 7;
        int srow = row < Nc ? row : Nc - 1;
        short8 kv = *(const short8*)(base + (size_t)srow * rs + Cc + u * 8);
        *(short8*)(Ks + row * 64 + ((u ^ (row & 7)) << 3)) = kv;
        short8 vv = *(const short8*)(base + (size_t)srow * rs + 2 * Cc + u * 8);
        #pragma unroll
        for (int w = 0; w < 8; ++w) {
            __hip_bfloat16 bv = ((const __hip_bfloat16*)&vv)[w];
            VT[(u * 8 + w) * VTS + row] = (_Float16)__bfloat162float(bv);
        }
    }
    __syncthreads();

    const int wv = t >> 6, lane = t & 63;
    const int g = lane >> 4, c16 = lane & 15;
    const float KS = SCALE_H * LOG2E;

    for (int qt = wv; qt < NQT; qt += 4) {
        int qrow = qt * 16 + c16;
        int sq = qrow < Nc ? qrow : Nc - 1;
        const __hip_bfloat16* qb = base + (size_t)sq * rs + g * 8;
        short8 bq0 = *(const short8*)(qb);
        short8 bq1 = *(const short8*)(qb + 32);

        float4a acc[NKT];
        #pragma unroll
        for (int kt = 0; kt < NKT; ++kt) acc[kt] = (float4a)0.f;
        #pragma unroll
        for (int kt = 0; kt < NKT; ++kt) {
            int r = kt * 16 + c16;
            short8 a0 = *(const short8*)(Ks + r * 64 + ((g ^ (r & 7)) << 3));
            short8 a1 = *(const short8*)(Ks + r * 64 + (((4 + g) ^ (r & 7)) << 3));
            acc[kt] = __builtin_amdgcn_mfma_f32_16x16x32_bf16(a0, bq0, acc[kt], 0, 0, 0);
            acc[kt] = __builtin_amdgcn_mfma_f32_16x16x32_bf16(a1, bq1, acc[kt], 0, 0, 0);
        }

        float m = -INFINITY;
        #pragma unroll
        for (int kt = 0; kt < NKT; ++kt) {
            #pragma unroll
            for (int j = 0; j < 4; ++j) {
                int key = kt * 16 + g * 4 + j;
                float v = (key < Nc) ? acc[kt][j] * KS : -INFINITY;
                acc[kt][j] = v;
                m = fmaxf(m, v);
            }
        }
        m = fmaxf(m, __shfl_xor(m, 16));
        m = fmaxf(m, __shfl_xor(m, 32));

        float sum = 0.f;
        half4 pb[NKT];
        #pragma unroll
        for (int kt = 0; kt < NKT; ++kt) {
            #pragma unroll
            for (int j = 0; j < 4; ++j) {
                float e = exp2f(acc[kt][j] - m);
                sum += e;
                pb[kt][j] = (_Float16)e;
            }
        }
        sum += __shfl_xor(sum, 16);
        sum += __shfl_xor(sum, 32);
        float inv = 1.f / sum;

        float4a oa[4];
        #pragma unroll
        for (int dt = 0; dt < 4; ++dt) oa[dt] = (float4a)0.f;
        #pragma unroll
        for (int kt = 0; kt < NKT; ++kt) {
            #pragma unroll
            for (int dt = 0; dt < 4; ++dt) {
                half4 av = *(const half4*)(VT + (size_t)(dt * 16 + c16) * VTS
                                              + kt * 16 + g * 4);
                oa[dt] = __builtin_amdgcn_mfma_f32_16x16x16f16(av, pb[kt], oa[dt], 0, 0, 0);
            }
        }

        if (qrow < Nc) {
            __hip_bfloat16* ob = o + ((size_t)b * Nc + qrow) * Cc + h * HDc;
            #pragma unroll
            for (int dt = 0; dt < 4; ++dt) {
                __hip_bfloat16 tmp[4];
                #pragma unroll
                for (int j = 0; j < 4; ++j)
                    tmp[j] = __float2bfloat16(oa[dt][j] * inv);
                *(s16x4*)(ob + dt * 16 + g * 4) = *(const s16x4*)tmp;
            }
        }
    }
}

// =====================================================================
extern "C" void kernel_launch(void* const* d_in, const int* in_sizes, int n_in,
                              void* d_out, int out_size, void* d_ws, size_t ws_size,
                              hipStream_t stream)
{
    const float* x       = (const float*)d_in[0];
    const float* y       = (const float*)d_in[1];
    const float* latents = (const float*)d_in[2];
    const float* scale_a = (const float*)d_in[3];
    const float* scale_v = (const float*)d_in[4];

    float* out = (float*)d_out;

    // weight offsets within each stream's wT region (elements)
    constexpr size_t WSTREAM = 7077888;
    constexpr size_t OFF_QKV = 0;
    constexpr size_t OFF_PROJ = 2304 * 768;
    constexpr size_t OFF_FC1 = OFF_PROJ + 768 * 768;
    constexpr size_t OFF_FC2 = OFF_FC1 + 3072 * 768;

    constexpr size_t FRONT = ((size_t)Bc * Lc * NCAT + (size_t)Bc * Lc * Cc) * 4;
    constexpr size_t NEED_BATCH = FRONT
        + 2 * (size_t)Mrows * Cc * 2      // tbuf x2 streams (bf16)
        + 2 * (size_t)Mrows * DFFc * 2    // big  x2 streams (bf16)
        + 2 * WSTREAM * 2;                // wT

    float* ws = (float*)d_ws;
    float* scores = ws;
    float* fusedb = scores + (size_t)Bc * Lc * NCAT;

    const bool batched = ws_size >= NEED_BATCH;

    __hip_bfloat16* tbuf = (__hip_bfloat16*)(fusedb + (size_t)Bc * Lc * Cc);
    __hip_bfloat16* big;
    __hip_bfloat16* wT;
    if (batched) {
        big = tbuf + 2 * (size_t)Mrows * Cc;
        wT  = big + 2 * (size_t)Mrows * DFFc;
    } else {
        big = tbuf + (size_t)Mrows * Cc;
        wT  = big + (size_t)Mrows * DFFc;
    }

    // ---- latent bottleneck fusion ----
    lat_scores_ker<<<Bc * NCAT / 4, 256, 0, stream>>>(x, y, latents, scores);
    lat_softmax_ker<<<Bc, 256, 0, stream>>>(scores);
    lat_fused_ker<<<dim3(Bc, 12), 256, 0, stream>>>(x, y, scores, fusedb);
    inject_ker<<<2 * Mrows, 256, 0, stream>>>(x, y, fusedb, scale_a, scale_v, out);

    // ---- weight cast+transpose (all 8 at once) ----
    WArgs wa;
    for (int p = 0; p < 2; ++p) {
        int basei = 5 + 12 * p;
        wa.src[p * 4 + 0] = (const float*)d_in[basei + 2];   // qkv_w
        wa.src[p * 4 + 1] = (const float*)d_in[basei + 4];   // proj_w
        wa.src[p * 4 + 2] = (const float*)d_in[basei + 8];   // fc1_w
        wa.src[p * 4 + 3] = (const float*)d_in[basei + 10];  // fc2_w
        wa.dst[p * 4 + 0] = wT + p * WSTREAM + OFF_QKV;
        wa.dst[p * 4 + 1] = wT + p * WSTREAM + OFF_PROJ;
        wa.dst[p * 4 + 2] = wT + p * WSTREAM + OFF_FC1;
        wa.dst[p * 4 + 3] = wT + p * WSTREAM + OFF_FC2;
    }
    wcast_all_ker<<<dim3(6912, 1, 2), 256, 0, stream>>>(wa);

    const float* g1[2], *b1[2], *qkvb[2], *projb[2], *g2[2], *b2[2], *fc1b[2], *fc2b[2];
    for (int p = 0; p < 2; ++p) {
        int basei = 5 + 12 * p;
        g1[p]    = (const float*)d_in[basei + 0];
        b1[p]    = (const float*)d_in[basei + 1];
        qkvb[p]  = (const float*)d_in[basei + 3];
        projb[p] = (const float*)d_in[basei + 5];
        g2[p]    = (const float*)d_in[basei + 6];
        b2[p]    = (const float*)d_in[basei + 7];
        fc1b[p]  = (const float*)d_in[basei + 9];
        fc2b[p]  = (const float*)d_in[basei + 11];
    }

    const size_t MC = (size_t)Mrows * Cc;
    const size_t MQKV = (size_t)Mrows * 2304;
    const size_t MFF = (size_t)Mrows * DFFc;

    if (batched) {
        // buffers: tbuf[z] = ln-out then attn-out then ln2-out; big[z] = qkv/fc1 out
        ln_ker<<<dim3(Mrows, 1, 2), 256, 0, stream>>>(
            out, MC, g1[0], b1[0], g1[1], b1[1], tbuf, MC);
        gemm_bf16_ker<0, __hip_bfloat16><<<dim3(18, 49, 2), 256, 0, stream>>>(
            tbuf, MC, wT + OFF_QKV, WSTREAM, qkvb[0], qkvb[1],
            (const float*)out, 0, big, MQKV, Mrows, 2304, 768);
        attn_mfma_ker<<<dim3(Hc, Bc, 2), 256, 0, stream>>>(big, MQKV, tbuf, MC);
        gemm_bf16_ker<2, float><<<dim3(6, 49, 2), 256, 0, stream>>>(
            tbuf, MC, wT + OFF_PROJ, WSTREAM, projb[0], projb[1],
            (const float*)out, MC, out, MC, Mrows, 768, 768);
        ln_ker<<<dim3(Mrows, 1, 2), 256, 0, stream>>>(
            out, MC, g2[0], b2[0], g2[1], b2[1], tbuf, MC);
        gemm_bf16_ker<1, __hip_bfloat16><<<dim3(24, 49, 2), 256, 0, stream>>>(
            tbuf, MC, wT + OFF_FC1, WSTREAM, fc1b[0], fc1b[1],
            (const float*)out, 0, big, MFF, Mrows, 3072, 768);
        gemm_bf16_ker<2, float><<<dim3(6, 49, 2), 256, 0, stream>>>(
            big, MFF, wT + OFF_FC2, WSTREAM, fc2b[0], fc2b[1],
            (const float*)out, MC, out, MC, Mrows, 768, 3072);
    } else {
        for (int p = 0; p < 2; ++p) {
            float* X = out + (size_t)p * MC;
            __hip_bfloat16* wb = wT + p * WSTREAM;
            ln_ker<<<dim3(Mrows, 1, 1), 256, 0, stream>>>(
                X, 0, g1[p], b1[p], g1[p], b1[p], tbuf, 0);
            gemm_bf16_ker<0, __hip_bfloat16><<<dim3(18, 49, 1), 256, 0, stream>>>(
                tbuf, 0, wb + OFF_QKV, 0, qkvb[p], qkvb[p],
                (const float*)X, 0, big, 0, Mrows, 2304, 768);
            attn_mfma_ker<<<dim3(Hc, Bc, 1), 256, 0, stream>>>(big, 0, tbuf, 0);
            gemm_bf16_ker<2, float><<<dim3(6, 49, 1), 256, 0, stream>>>(
                tbuf, 0, wb + OFF_PROJ, 0, projb[p], projb[p],
                (const float*)X, 0, X, 0, Mrows, 768, 768);
            ln_ker<<<dim3(Mrows, 1, 1), 256, 0, stream>>>(
                X, 0, g2[p], b2[p], g2[p], b2[p], tbuf, 0);
            gemm_bf16_ker<1, __hip_bfloat16><<<dim3(24, 49, 1), 256, 0, stream>>>(
                tbuf, 0, wb + OFF_FC1, 0, fc1b[p], fc1b[p],
                (const float*)X, 0, big, 0, Mrows, 3072, 768);
            gemm_bf16_ker<2, float><<<dim3(6, 49, 1), 256, 0, stream>>>(
                big, 0, wb + OFF_FC2, 0, fc2b[p], fc2b[p],
                (const float*)X, 0, X, 0, Mrows, 768, 3072);
        }
    }
}